// Round 10
// baseline (856.151 us; speedup 1.0000x reference)
//
#include <hip/hip_runtime.h>
#include <math.h>

// Round 10: rnd-9 + software-pipelined s-loop.
//   - Weights double-buffered in regs: wb[2][hi/lo][7 tiles]; s+1's 14 L2
//     loads issue during s's 42 MFMAs (~200cyc each side -> latency hidden).
//   - X-fragments double-buffered: xb[2][plane][rt] (4 ds_read_b128 early).
//   - At s==3 prefetch NEXT LAYER's s=0 weights -> they land under the
//     epilogue's sp100/split VALU.
//   - MFMA stream reordered term-outer: consecutive ops hit different acc
//     registers (14 independent chains of depth 3).
// Else identical to round 9: 256 thr / 4 waves / 128 rows, rt=2, split-fp16
// 3-term, bias folded at k=100, HW transcendentals, plane-separated hi/lo
// fp16 LDS with ((m&7)<<4) swizzle, no barriers in the layer loop.

typedef _Float16 half8 __attribute__((ext_vector_type(8)));
typedef _Float16 half4v __attribute__((ext_vector_type(4)));
typedef float f32x4 __attribute__((ext_vector_type(4)));

#define TPB 256
#define RPB 128

__device__ __forceinline__ float sp100(float x) {
    // softplus(100x)/100 = max(x,0) + ln2/100 * log2(1 + 2^(-(100/ln2)*|x|))
    float t = __builtin_amdgcn_exp2f(-144.26950408889634f * fabsf(x));
    return fmaxf(x, 0.0f) + 0.0069314718055994531f * __builtin_amdgcn_logf(1.0f + t);
}

// byte offset into an fp16 plane [128 rows][128 k]; row stride 256 B;
// 16B-granule XOR swizzle
__device__ __forceinline__ int xhb(int m, int k) {
    return ((m << 8) + (k << 1)) ^ ((m & 7) << 4);
}

__global__ __launch_bounds__(TPB, 2) void mlp_fwd(
    const float* __restrict__ inp,
    const uint4* __restrict__ wpk,   // 7 layers x [term][s*7+t][lane], bias at k=100
    const float* __restrict__ W0, const float* __restrict__ b0,
    const float* __restrict__ W8, const float* __restrict__ b8,
    float* __restrict__ out)
{
    __shared__ _Float16 XH[RPB * 128];   // 32 KB hi plane
    __shared__ _Float16 XL[RPB * 128];   // 32 KB lo plane
    __shared__ float inps[RPB * 2];
    __shared__ float w0s[304];

    const int tid  = threadIdx.x;
    const int lane = tid & 63;
    const int wid  = tid >> 6;           // wave 0..3 -> rows wid*32..+31
    const int g    = lane >> 4;
    const int bid  = blockIdx.x;

    if (tid < RPB) {
        float2 v = *reinterpret_cast<const float2*>(inp + ((size_t)bid * RPB + tid) * 2);
        inps[tid * 2]     = v.x;
        inps[tid * 2 + 1] = v.y;
    }
    for (int q = tid; q < 304; q += TPB)
        w0s[q] = (q < 200) ? W0[q] : b0[q - 200];
    __syncthreads();   // the only barrier

    // ---- L0: [2 -> 100]; wave fills its own 32 rows; col 100 = 1.0; pad 0 ----
#pragma unroll
    for (int it = 0; it < 16; ++it) {
        int m = wid * 32 + it * 2 + (lane >> 5);
        int q = lane & 31;               // col quad: cols 4q..4q+3
        float i0 = inps[m * 2], i1 = inps[m * 2 + 1];
        half4v hh, hl;
#pragma unroll
        for (int p = 0; p < 4; ++p) {
            int c = q * 4 + p;
            float y = (c < 100)
                ? sp100(fmaf(i0, w0s[c * 2], fmaf(i1, w0s[c * 2 + 1], w0s[200 + c])))
                : ((c == 100) ? 1.0f : 0.0f);
            _Float16 h = (_Float16)y;
            hh[p] = h;
            hl[p] = (_Float16)(y - (float)h);
        }
        *reinterpret_cast<half4v*>(reinterpret_cast<char*>(XH) + xhb(m, q * 4)) = hh;
        *reinterpret_cast<half4v*>(reinterpret_cast<char*>(XL) + xhb(m, q * 4)) = hl;
    }

    // ---- register pipeline buffers ----
    half8 wb[2][2][7];   // [buf][hi=0/lo=1][tile]
    half8 xb[2][2][2];   // [buf][plane hi/lo][rt]

    const half8* __restrict__ w8p = reinterpret_cast<const half8*>(wpk);

    // prologue: layer 1, s = 0
#pragma unroll
    for (int t = 0; t < 7; ++t) {
        wb[0][0][t] = w8p[t * 64 + lane];            // s=0: (0*7+t)
        wb[0][1][t] = w8p[1792 + t * 64 + lane];
    }
#pragma unroll
    for (int rt = 0; rt < 2; ++rt) {
        int m = wid * 32 + rt * 16 + (lane & 15);
        xb[0][0][rt] = *reinterpret_cast<const half8*>(
                           reinterpret_cast<const char*>(XH) + xhb(m, g * 8));
        xb[0][1][rt] = *reinterpret_cast<const half8*>(
                           reinterpret_cast<const char*>(XL) + xhb(m, g * 8));
    }

    // ---- layers 1..7, no barriers (wave-private rows) ----
#pragma unroll 1
    for (int l = 1; l <= 7; ++l) {
        const half8* __restrict__ wl = w8p + (size_t)(l - 1) * 3584;

        f32x4 acc[2][7];
#pragma unroll
        for (int rt = 0; rt < 2; ++rt)
#pragma unroll
            for (int t = 0; t < 7; ++t) acc[rt][t] = f32x4{0.f, 0.f, 0.f, 0.f};

#pragma unroll
        for (int s = 0; s < 4; ++s) {
            const int cb = s & 1;
            const int nb = cb ^ 1;

            // ---- prefetch phase: issue BEFORE the MFMA stream ----
            if (s < 3) {
#pragma unroll
                for (int t = 0; t < 7; ++t) {
                    wb[nb][0][t] = wl[((s + 1) * 7 + t) * 64 + lane];
                    wb[nb][1][t] = wl[1792 + ((s + 1) * 7 + t) * 64 + lane];
                }
#pragma unroll
                for (int rt = 0; rt < 2; ++rt) {
                    int m  = wid * 32 + rt * 16 + (lane & 15);
                    int k0 = (s + 1) * 32 + g * 8;
                    xb[nb][0][rt] = *reinterpret_cast<const half8*>(
                                        reinterpret_cast<const char*>(XH) + xhb(m, k0));
                    xb[nb][1][rt] = *reinterpret_cast<const half8*>(
                                        reinterpret_cast<const char*>(XL) + xhb(m, k0));
                }
            } else if (l < 7) {
                // next layer's s=0 weights -> land under the epilogue VALU
#pragma unroll
                for (int t = 0; t < 7; ++t) {
                    wb[0][0][t] = wl[3584 + t * 64 + lane];
                    wb[0][1][t] = wl[3584 + 1792 + t * 64 + lane];
                }
            }

            // ---- MFMA stream, term-outer (consecutive ops independent) ----
#pragma unroll
            for (int t = 0; t < 7; ++t)
#pragma unroll
                for (int rt = 0; rt < 2; ++rt)
                    acc[rt][t] = __builtin_amdgcn_mfma_f32_16x16x32_f16(
                        wb[cb][0][t], xb[cb][0][rt], acc[rt][t], 0, 0, 0);
#pragma unroll
            for (int t = 0; t < 7; ++t)
#pragma unroll
                for (int rt = 0; rt < 2; ++rt)
                    acc[rt][t] = __builtin_amdgcn_mfma_f32_16x16x32_f16(
                        wb[cb][0][t], xb[cb][1][rt], acc[rt][t], 0, 0, 0);
#pragma unroll
            for (int t = 0; t < 7; ++t)
#pragma unroll
                for (int rt = 0; rt < 2; ++rt)
                    acc[rt][t] = __builtin_amdgcn_mfma_f32_16x16x32_f16(
                        wb[cb][1][t], xb[cb][0][rt], acc[rt][t], 0, 0, 0);
        }

        if (l < 7) {
            const int Nl = (l == 3) ? 98 : 100;
#pragma unroll
            for (int rt = 0; rt < 2; ++rt) {
                int m = wid * 32 + rt * 16 + (lane & 15);
#pragma unroll
                for (int t = 0; t < 7; ++t) {
                    half4v hh, hl;
#pragma unroll
                    for (int i = 0; i < 4; ++i) {
                        int n = 16 * t + 4 * g + i;
                        float y = (n < Nl) ? sp100(acc[rt][t][i])
                                           : ((n == Nl) ? 1.0f : 0.0f);
                        _Float16 h = (_Float16)y;
                        hh[i] = h;
                        hl[i] = (_Float16)(y - (float)h);
                    }
                    if (l != 3) {
                        *reinterpret_cast<half4v*>(
                            reinterpret_cast<char*>(XH) + xhb(m, 16 * t + 4 * g)) = hh;
                        *reinterpret_cast<half4v*>(
                            reinterpret_cast<char*>(XL) + xhb(m, 16 * t + 4 * g)) = hl;
                    } else {   // col shift +2: scalar b16 (granule-crossing)
#pragma unroll
                        for (int i = 0; i < 4; ++i) {
                            int c = 16 * t + 4 * g + i + 2;
                            *reinterpret_cast<_Float16*>(
                                reinterpret_cast<char*>(XH) + xhb(m, c)) = hh[i];
                            *reinterpret_cast<_Float16*>(
                                reinterpret_cast<char*>(XL) + xhb(m, c)) = hl[i];
                        }
                    }
                }
            }
            if (l == 3 && lane < 32) {   // skip-concat: inputs -> cols 0,1
                int m = wid * 32 + lane;
#pragma unroll
                for (int c = 0; c < 2; ++c) {
                    float v = inps[m * 2 + c];
                    _Float16 h = (_Float16)v;
                    *reinterpret_cast<_Float16*>(
                        reinterpret_cast<char*>(XH) + xhb(m, c)) = h;
                    *reinterpret_cast<_Float16*>(
                        reinterpret_cast<char*>(XL) + xhb(m, c)) = (_Float16)(v - (float)h);
                }
            }
            // reload xb[0] for next layer's s=0 (same-wave LDS: in-order, safe)
#pragma unroll
            for (int rt = 0; rt < 2; ++rt) {
                int m = wid * 32 + rt * 16 + (lane & 15);
                xb[0][0][rt] = *reinterpret_cast<const half8*>(
                                   reinterpret_cast<const char*>(XH) + xhb(m, g * 8));
                xb[0][1][rt] = *reinterpret_cast<const half8*>(
                                   reinterpret_cast<const char*>(XL) + xhb(m, g * 8));
            }
        } else {
            // ---- fused L8: dot with W8 (b7 already inside acc), reduce ----
            float w84[7][4];
#pragma unroll
            for (int t = 0; t < 6; ++t) {
                float4 w4 = *reinterpret_cast<const float4*>(W8 + 16 * t + 4 * g);
                w84[t][0] = w4.x; w84[t][1] = w4.y; w84[t][2] = w4.z; w84[t][3] = w4.w;
            }
#pragma unroll
            for (int i = 0; i < 4; ++i) {
                int n = 96 + 4 * g + i;
                w84[6][i] = (n < 100) ? W8[n] : 0.0f;
            }
            float p8[2] = {0.0f, 0.0f};
#pragma unroll
            for (int rt = 0; rt < 2; ++rt)
#pragma unroll
                for (int t = 0; t < 7; ++t)
#pragma unroll
                    for (int i = 0; i < 4; ++i)
                        p8[rt] = fmaf(w84[t][i], sp100(acc[rt][t][i]), p8[rt]);
            float b8v = b8[0];
#pragma unroll
            for (int rt = 0; rt < 2; ++rt) {
                float v = p8[rt];
                v += __shfl_xor(v, 16);
                v += __shfl_xor(v, 32);
                if (lane < 16)
                    out[(size_t)bid * RPB + wid * 32 + rt * 16 + lane] = v + b8v;
            }
        }
    }
}

// Pack W1..W7 (+ biases b1..b7 at k=100) -> per-layer [term][s*7+t][lane] half8:
// half jj at k=32s+8*(lane>>4)+jj, n=16t+(lane&15);
//   k<100: W[n][k];  k==100: b[n];  else 0.  (zero outside n<Nl)
// term0=(f16)val, term1=(f16)(val-(float)(f16)val).
__global__ void pack_weights(
    const float* __restrict__ W1, const float* __restrict__ W2,
    const float* __restrict__ W3, const float* __restrict__ W4,
    const float* __restrict__ W5, const float* __restrict__ W6,
    const float* __restrict__ W7,
    const float* __restrict__ b1, const float* __restrict__ b2,
    const float* __restrict__ b3, const float* __restrict__ b4,
    const float* __restrict__ b5, const float* __restrict__ b6,
    const float* __restrict__ b7,
    uint4* __restrict__ wpk)
{
    const float* Wt[7] = {W1, W2, W3, W4, W5, W6, W7};
    const float* Bt[7] = {b1, b2, b3, b4, b5, b6, b7};
    const float* W = Wt[blockIdx.x];
    const float* B = Bt[blockIdx.x];
    const int Nl = (blockIdx.x == 2) ? 98 : 100;   // layer 3 outputs 98
    for (int e = threadIdx.x; e < 3584; e += 256) {
        int term = e / 1792;
        int r    = e - term * 1792;
        int lane = r & 63;
        int st   = r >> 6;
        int s    = st / 7;
        int t    = st - s * 7;
        union { _Float16 h[8]; uint4 v; } pk;
#pragma unroll
        for (int jj = 0; jj < 8; ++jj) {
            int k = s * 32 + (lane >> 4) * 8 + jj;
            int n = t * 16 + (lane & 15);
            float val = 0.0f;
            if (n < Nl) {
                if (k < 100)       val = W[n * 100 + k];
                else if (k == 100) val = B[n];
            }
            _Float16 h = (_Float16)val;
            pk.h[jj] = term ? (_Float16)(val - (float)h) : h;
        }
        wpk[blockIdx.x * 3584 + term * 1792 + r] = pk.v;
    }
}

extern "C" void kernel_launch(void* const* d_in, const int* in_sizes, int n_in,
                              void* d_out, int out_size, void* d_ws, size_t ws_size,
                              hipStream_t stream)
{
    const float* inp = (const float*)d_in[0];
    const float* W[9];
    const float* B[9];
    for (int l = 0; l < 9; ++l) {
        W[l] = (const float*)d_in[1 + 2 * l];
        B[l] = (const float*)d_in[2 + 2 * l];
    }
    uint4* wpk = (uint4*)d_ws;             // 7*3584*16 = 401,408 B
    float* out = (float*)d_out;
    const int N = in_sizes[0] / 2;         // 1,048,576 rows

    pack_weights<<<7, 256, 0, stream>>>(W[1], W[2], W[3], W[4], W[5], W[6], W[7],
                                        B[1], B[2], B[3], B[4], B[5], B[6], B[7],
                                        wpk);
    mlp_fwd<<<N / RPB, TPB, 0, stream>>>(inp, wpk,
                                         W[0], B[0], W[8], B[8],
                                         out);
}